// Round 4
// baseline (182.319 us; speedup 1.0000x reference)
//
#include <hip/hip_runtime.h>

typedef _Float16 f16;
typedef _Float16 f16x4 __attribute__((ext_vector_type(4)));
typedef _Float16 f16x8 __attribute__((ext_vector_type(8)));
typedef float    f32x4 __attribute__((ext_vector_type(4)));

__device__ __forceinline__ float sigmf(float x) {
    return __builtin_amdgcn_rcpf(1.0f + __expf(-x));
}
__device__ __forceinline__ float tanhf_fast(float x) {
    return 2.0f * sigmf(2.0f * x) - 1.0f;   // saturates correctly for large |x|
}

#define MFMA16(A, B, C) __builtin_amdgcn_mfma_f32_16x16x32_f16((A), (B), (C), 0, 0, 0)

// strides in f16 elems (all chosen so 16-lane row-strides hit >=8 distinct banks -> <=2-way)
constexpr int SIN_STR = 104;   // [16 batch][96+8]: h(0:64) | x(64:69) | 1.0@69 | 0(70:96)
constexpr int Z1_STR  = 264;   // [16][256+8]
constexpr int Z2_STR  = 72;    // [32][64+8]
constexpr int Z34_STR = 40;    // [32][32+8]

// union byte offsets (staging scratch for weights overlays runtime buffers)
// gates staging [256][104] f16 = 53248 B is the max user
constexpr int Z1_OFF = 0;       // 16*264*2 = 8448
constexpr int Z2_OFF = 16896;   // 32*72*2  = 4608
constexpr int Z3_OFF = 21504;   // 32*40*2  = 2560
constexpr int Z4_OFF = 24064;   // 32*40*2  = 2560

__global__ void __launch_bounds__(256)
__attribute__((amdgpu_waves_per_eu(2, 2)))
lstmdqn_coop(const float* __restrict__ xg,  const float* __restrict__ h0g,
             const float* __restrict__ c0g,
             const float* __restrict__ Wih, const float* __restrict__ Whh,
             const float* __restrict__ bih, const float* __restrict__ bhh,
             const float* __restrict__ w1p, const float* __restrict__ b1p,
             const float* __restrict__ w2p, const float* __restrict__ b2p,
             const float* __restrict__ w3p, const float* __restrict__ b3p,
             const float* __restrict__ w4p, const float* __restrict__ b4p,
             const float* __restrict__ whp, const float* __restrict__ bhp,
             float* __restrict__ out, int Bsz, int ntiles, int nit) {
    __shared__ __align__(16) char uni[53248];
    __shared__ __align__(16) f16 sIN[2][16 * SIN_STR];
    __shared__ __align__(16) f16 sW3[32 * 72];   // persistent tail weights
    __shared__ __align__(16) f16 sW4[16 * Z34_STR];
    __shared__ __align__(16) f16 sWh[16 * Z34_STR];
    f16* sWS = (f16*)uni;
    f16* sZ1 = (f16*)(uni + Z1_OFF);
    f16* sZ2 = (f16*)(uni + Z2_OFF);
    f16* sZ3 = (f16*)(uni + Z3_OFF);
    f16* sZ4 = (f16*)(uni + Z4_OFF);

    const int tid  = threadIdx.x;
    const int w    = tid >> 6;     // wave 0..3
    const int l    = tid & 63;
    const int lrow = l & 15;       // batch col within tile / weight row within m-tile
    const int hi   = l >> 4;       // k-chunk / D-row-quad selector

    // ================= SETUP: weights -> LDS scratch -> register A-fragments ==============
    // ---- gates: W_g rows n (i,f,g,o stacked), cols k: [Whh | Wih | bias@69 | 0] ----
    for (int idx = tid; idx < 256 * SIN_STR; idx += 256) {
        int n = idx / SIN_STR, k = idx - n * SIN_STR;
        float v = 0.0f;
        if (k < 64)       v = Whh[n * 64 + k];
        else if (k < 69)  v = Wih[n * 5 + (k - 64)];
        else if (k == 69) v = bih[n] + bhh[n];
        sWS[idx] = (f16)v;
    }
    __syncthreads();
    f16x8 Wg[4][3];
    #pragma unroll
    for (int mi = 0; mi < 4; ++mi) {
        int n = 16 * (w + 4 * mi) + lrow;
        #pragma unroll
        for (int kt = 0; kt < 3; ++kt)
            Wg[mi][kt] = *reinterpret_cast<const f16x8*>(&sWS[n * SIN_STR + kt * 32 + 8 * hi]);
    }
    __syncthreads();
    // ---- W1 [256][64] -> [256][72] ----
    for (int idx = tid; idx < 256 * 72; idx += 256) {
        int n = idx / 72, k = idx - n * 72;
        sWS[idx] = (f16)((k < 64) ? w1p[n * 64 + k] : 0.0f);
    }
    __syncthreads();
    f16x8 W1f[4][2];
    #pragma unroll
    for (int mi = 0; mi < 4; ++mi) {
        int n = 16 * (w + 4 * mi) + lrow;
        #pragma unroll
        for (int kt = 0; kt < 2; ++kt)
            W1f[mi][kt] = *reinterpret_cast<const f16x8*>(&sWS[n * 72 + kt * 32 + 8 * hi]);
    }
    __syncthreads();
    // ---- W2 [64][256] -> [64][264] ----
    for (int idx = tid; idx < 64 * Z1_STR; idx += 256) {
        int n = idx / Z1_STR, k = idx - n * Z1_STR;
        sWS[idx] = (f16)((k < 256) ? w2p[n * 256 + k] : 0.0f);
    }
    __syncthreads();
    f16x8 W2f[8];
    {
        int n = 16 * w + lrow;
        #pragma unroll
        for (int kt = 0; kt < 8; ++kt)
            W2f[kt] = *reinterpret_cast<const f16x8*>(&sWS[n * Z1_STR + kt * 32 + 8 * hi]);
    }
    __syncthreads();
    // ---- persistent tail weights (outside union) ----
    for (int idx = tid; idx < 32 * 72; idx += 256) {
        int n = idx / 72, k = idx - n * 72;
        sW3[idx] = (f16)((k < 64) ? w3p[n * 64 + k] : 0.0f);
    }
    for (int idx = tid; idx < 16 * Z34_STR; idx += 256) {
        int n = idx / Z34_STR, k = idx - n * Z34_STR;
        sW4[idx] = (f16)((k < 32) ? w4p[n * 32 + k] : 0.0f);
        sWh[idx] = (f16)((n < 3 && k < 16) ? whp[n * 16 + k] : 0.0f);
    }
    // ---- sIN constant zones: col 69 = 1.0 (bias feature), 70:96 = 0, both buffers ----
    for (int idx = tid; idx < 2 * 16 * 27; idx += 256) {
        int b = idx / (16 * 27), r = (idx / 27) & 15, k = 69 + (idx % 27);
        sIN[b][r * SIN_STR + k] = (f16)((k == 69) ? 1.0f : 0.0f);
    }
    // ---- sZ4 zero-pad cols 16:32 (head K padded to 32) ----
    for (int idx = tid; idx < 32 * 16; idx += 256) {
        int r = idx / 16, k = 16 + (idx & 15);
        sZ4[r * Z34_STR + k] = (f16)0.0f;
    }
    // ---- bias registers ----
    float bz1[4][4], bz2[4], bz3[4], bz4[4];
    #pragma unroll
    for (int mi = 0; mi < 4; ++mi)
        #pragma unroll
        for (int q = 0; q < 4; ++q)
            bz1[mi][q] = b1p[16 * (w + 4 * mi) + 4 * hi + q];
    #pragma unroll
    for (int q = 0; q < 4; ++q) {
        bz2[q] = b2p[16 * w + 4 * hi + q];
        bz3[q] = b3p[16 * (w & 1) + 4 * hi + q];
        bz4[q] = b4p[4 * hi + q];
    }
    const float bh0 = bhp[0], bh1 = bhp[1], bh2 = bhp[2];
    __syncthreads();

    // ================= MAIN LOOP: 16-batch tiles, tail every 2 tiles ==============
    const int tb = blockIdx.x * nit;
    f16* sIN0 = &sIN[0][0];
    f16* sIN1 = &sIN[1][0];

    // prologue prefetch for it=0
    float4 hpre = {0, 0, 0, 0}, cpre = {0, 0, 0, 0}, x0pre = {0, 0, 0, 0}, x1pre = {0, 0, 0, 0};
    {
        int rb = tb * 16;
        if (tb < ntiles) {
            hpre = *reinterpret_cast<const float4*>(h0g + (size_t)rb * 64 + tid * 4);
            cpre = *reinterpret_cast<const float4*>(c0g + (size_t)(rb + lrow) * 64 + 16 * w + 4 * hi);
            if (tid < 20) {
                x0pre = *reinterpret_cast<const float4*>(xg + (size_t)rb * 5 + tid * 4);
                x1pre = *reinterpret_cast<const float4*>(xg + (size_t)Bsz * 5 + (size_t)rb * 5 + tid * 4);
            }
        }
    }

    #pragma unroll 1
    for (int it = 0; it < nit; ++it) {
        const int tile = tb + it;

        // ---- stage h0 + x0 into sIN0 from prefetch regs ----
        {
            int hr = tid >> 4, hc = (tid & 15) * 4;
            f16x4 hv = { (f16)hpre.x, (f16)hpre.y, (f16)hpre.z, (f16)hpre.w };
            *reinterpret_cast<f16x4*>(&sIN0[hr * SIN_STR + hc]) = hv;
            if (tid < 20) {
                float xv[4] = { x0pre.x, x0pre.y, x0pre.z, x0pre.w };
                #pragma unroll
                for (int e = 0; e < 4; ++e) {
                    int idx = tid * 4 + e;
                    sIN0[(idx / 5) * SIN_STR + 64 + (idx % 5)] = (f16)xv[e];
                }
            }
        }
        __syncthreads();   // A: staging visible

        // ---- LSTM step t=0: read sIN0, write h -> sIN1 (+ x1 -> sIN1) ----
        float cnew[4];
        {
            f16x8 b0 = *reinterpret_cast<const f16x8*>(&sIN0[lrow * SIN_STR +  0 + 8 * hi]);
            f16x8 b1 = *reinterpret_cast<const f16x8*>(&sIN0[lrow * SIN_STR + 32 + 8 * hi]);
            f16x8 b2 = *reinterpret_cast<const f16x8*>(&sIN0[lrow * SIN_STR + 64 + 8 * hi]);
            f32x4 acc[4];
            #pragma unroll
            for (int mi = 0; mi < 4; ++mi) {
                f32x4 a = { 0.f, 0.f, 0.f, 0.f };          // bias folded into k=69
                a = MFMA16(Wg[mi][0], b0, a);
                a = MFMA16(Wg[mi][1], b1, a);
                a = MFMA16(Wg[mi][2], b2, a);
                acc[mi] = a;
            }
            float cold[4] = { cpre.x, cpre.y, cpre.z, cpre.w };
            f16 hq[4];
            #pragma unroll
            for (int q = 0; q < 4; ++q) {
                float iv = sigmf(acc[0][q]);
                float fv = sigmf(acc[1][q]);
                float gv = tanhf_fast(acc[2][q]);
                float ov = sigmf(acc[3][q]);
                float c  = fv * cold[q] + iv * gv;
                cnew[q]  = c;
                hq[q]    = (f16)(ov * tanhf_fast(c));
            }
            f16x4 hv = { hq[0], hq[1], hq[2], hq[3] };
            *reinterpret_cast<f16x4*>(&sIN1[lrow * SIN_STR + 16 * w + 4 * hi]) = hv;
            if (tid < 20) {
                float xv[4] = { x1pre.x, x1pre.y, x1pre.z, x1pre.w };
                #pragma unroll
                for (int e = 0; e < 4; ++e) {
                    int idx = tid * 4 + e;
                    sIN1[(idx / 5) * SIN_STR + 64 + (idx % 5)] = (f16)xv[e];
                }
            }
        }
        __syncthreads();   // B

        // ---- LSTM step t=1: read sIN1, write z0 = relu(h2) -> sIN0 ----
        {
            f16x8 b0 = *reinterpret_cast<const f16x8*>(&sIN1[lrow * SIN_STR +  0 + 8 * hi]);
            f16x8 b1 = *reinterpret_cast<const f16x8*>(&sIN1[lrow * SIN_STR + 32 + 8 * hi]);
            f16x8 b2 = *reinterpret_cast<const f16x8*>(&sIN1[lrow * SIN_STR + 64 + 8 * hi]);
            f32x4 acc[4];
            #pragma unroll
            for (int mi = 0; mi < 4; ++mi) {
                f32x4 a = { 0.f, 0.f, 0.f, 0.f };
                a = MFMA16(Wg[mi][0], b0, a);
                a = MFMA16(Wg[mi][1], b1, a);
                a = MFMA16(Wg[mi][2], b2, a);
                acc[mi] = a;
            }
            f16 hq[4];
            #pragma unroll
            for (int q = 0; q < 4; ++q) {
                float iv = sigmf(acc[0][q]);
                float fv = sigmf(acc[1][q]);
                float gv = tanhf_fast(acc[2][q]);
                float ov = sigmf(acc[3][q]);
                float c  = fv * cnew[q] + iv * gv;
                float h  = ov * tanhf_fast(c);
                hq[q]    = (f16)fmaxf(h, 0.0f);            // z0 = relu
            }
            f16x4 hv = { hq[0], hq[1], hq[2], hq[3] };
            *reinterpret_cast<f16x4*>(&sIN0[lrow * SIN_STR + 16 * w + 4 * hi]) = hv;
        }
        __syncthreads();   // C

        // ---- z1 = relu(W1 . z0) -> sZ1 [16][256] ----
        {
            f16x8 a0 = *reinterpret_cast<const f16x8*>(&sIN0[lrow * SIN_STR +  0 + 8 * hi]);
            f16x8 a1 = *reinterpret_cast<const f16x8*>(&sIN0[lrow * SIN_STR + 32 + 8 * hi]);
            #pragma unroll
            for (int mi = 0; mi < 4; ++mi) {
                f32x4 a = { bz1[mi][0], bz1[mi][1], bz1[mi][2], bz1[mi][3] };
                a = MFMA16(W1f[mi][0], a0, a);
                a = MFMA16(W1f[mi][1], a1, a);
                f16x4 zv = { (f16)fmaxf(a[0], 0.f), (f16)fmaxf(a[1], 0.f),
                             (f16)fmaxf(a[2], 0.f), (f16)fmaxf(a[3], 0.f) };
                *reinterpret_cast<f16x4*>(&sZ1[lrow * Z1_STR + 16 * (w + 4 * mi) + 4 * hi]) = zv;
            }
        }
        __syncthreads();   // D

        // ---- z2 = relu(W2 . z1) -> sZ2 window row (it&1)*16 ----
        {
            f32x4 a = { bz2[0], bz2[1], bz2[2], bz2[3] };
            #pragma unroll
            for (int kt = 0; kt < 8; ++kt) {
                f16x8 zb = *reinterpret_cast<const f16x8*>(&sZ1[lrow * Z1_STR + kt * 32 + 8 * hi]);
                a = MFMA16(W2f[kt], zb, a);
            }
            f16x4 zv = { (f16)fmaxf(a[0], 0.f), (f16)fmaxf(a[1], 0.f),
                         (f16)fmaxf(a[2], 0.f), (f16)fmaxf(a[3], 0.f) };
            *reinterpret_cast<f16x4*>(&sZ2[((it & 1) * 16 + lrow) * Z2_STR + 16 * w + 4 * hi]) = zv;
        }

        // ---- prefetch next tile (overlaps tail + next staging wait) ----
        {
            int nt2 = tb + it + 1;
            if (nt2 < ntiles) {
                int rb = nt2 * 16;
                hpre = *reinterpret_cast<const float4*>(h0g + (size_t)rb * 64 + tid * 4);
                cpre = *reinterpret_cast<const float4*>(c0g + (size_t)(rb + lrow) * 64 + 16 * w + 4 * hi);
                if (tid < 20) {
                    x0pre = *reinterpret_cast<const float4*>(xg + (size_t)rb * 5 + tid * 4);
                    x1pre = *reinterpret_cast<const float4*>(xg + (size_t)Bsz * 5 + (size_t)rb * 5 + tid * 4);
                }
            }
        }

        // ---- tail every 2 tiles over 32 batch rows ----
        if ((it & 1) == 1 || it == nit - 1) {
            __syncthreads();   // E: sZ2 complete
            // z3 = relu(W3 . z2): tasks (mt = w&1, ntb = w>>1)
            {
                int mt = w & 1, ntb = w >> 1;
                f16x8 wf0 = *reinterpret_cast<const f16x8*>(&sW3[(16 * mt + lrow) * 72 +  0 + 8 * hi]);
                f16x8 wf1 = *reinterpret_cast<const f16x8*>(&sW3[(16 * mt + lrow) * 72 + 32 + 8 * hi]);
                f16x8 zb0 = *reinterpret_cast<const f16x8*>(&sZ2[(ntb * 16 + lrow) * Z2_STR +  0 + 8 * hi]);
                f16x8 zb1 = *reinterpret_cast<const f16x8*>(&sZ2[(ntb * 16 + lrow) * Z2_STR + 32 + 8 * hi]);
                f32x4 a = { bz3[0], bz3[1], bz3[2], bz3[3] };
                a = MFMA16(wf0, zb0, a);
                a = MFMA16(wf1, zb1, a);
                f16x4 zv = { (f16)fmaxf(a[0], 0.f), (f16)fmaxf(a[1], 0.f),
                             (f16)fmaxf(a[2], 0.f), (f16)fmaxf(a[3], 0.f) };
                *reinterpret_cast<f16x4*>(&sZ3[(ntb * 16 + lrow) * Z34_STR + 16 * mt + 4 * hi]) = zv;
            }
            __syncthreads();   // F
            // z4 = relu(W4 . z3): waves 0,1 (ntb = w)
            if (w < 2) {
                f16x8 wf = *reinterpret_cast<const f16x8*>(&sW4[lrow * Z34_STR + 8 * hi]);
                f16x8 zb = *reinterpret_cast<const f16x8*>(&sZ3[(w * 16 + lrow) * Z34_STR + 8 * hi]);
                f32x4 a = { bz4[0], bz4[1], bz4[2], bz4[3] };
                a = MFMA16(wf, zb, a);
                f16x4 zv = { (f16)fmaxf(a[0], 0.f), (f16)fmaxf(a[1], 0.f),
                             (f16)fmaxf(a[2], 0.f), (f16)fmaxf(a[3], 0.f) };
                *reinterpret_cast<f16x4*>(&sZ4[(w * 16 + lrow) * Z34_STR + 4 * hi]) = zv;
            }
            __syncthreads();   // G
            // head: waves 2,3 (ntb = w-2), out = Wh . z4r + bh
            if (w >= 2) {
                int ntb = w - 2;
                f16x8 wf = *reinterpret_cast<const f16x8*>(&sWh[lrow * Z34_STR + 8 * hi]);
                f16x8 zb = *reinterpret_cast<const f16x8*>(&sZ4[(ntb * 16 + lrow) * Z34_STR + 8 * hi]);
                f32x4 a = { 0.f, 0.f, 0.f, 0.f };
                a = MFMA16(wf, zb, a);
                if (hi == 0) {
                    int rowbase = (tb + (it & ~1)) * 16;
                    int rg = rowbase + ntb * 16 + lrow;
                    if (rg < ntiles * 16) {
                        out[(size_t)rg * 3 + 0] = a[0] + bh0;
                        out[(size_t)rg * 3 + 1] = a[1] + bh1;
                        out[(size_t)rg * 3 + 2] = a[2] + bh2;
                    }
                }
            }
            // no barrier needed: next iter's staging touches sIN only; barrier A re-syncs
        }
        (void)tile;
    }
}

extern "C" void kernel_launch(void* const* d_in, const int* in_sizes, int n_in,
                              void* d_out, int out_size, void* d_ws, size_t ws_size,
                              hipStream_t stream) {
    const float* x   = (const float*)d_in[0];
    const float* h0  = (const float*)d_in[1];
    const float* c0  = (const float*)d_in[2];
    const float* Wih = (const float*)d_in[3];
    const float* Whh = (const float*)d_in[4];
    const float* bih = (const float*)d_in[5];
    const float* bhh = (const float*)d_in[6];
    const float* w1  = (const float*)d_in[7];
    const float* b1  = (const float*)d_in[8];
    const float* w2  = (const float*)d_in[9];
    const float* b2  = (const float*)d_in[10];
    const float* w3  = (const float*)d_in[11];
    const float* b3  = (const float*)d_in[12];
    const float* w4  = (const float*)d_in[13];
    const float* b4  = (const float*)d_in[14];
    const float* wh  = (const float*)d_in[15];
    const float* bh  = (const float*)d_in[16];

    int Bsz    = in_sizes[1] / 64;         // h0 is [B, 64]
    int ntiles = (Bsz + 15) / 16;
    int grid   = 512;                      // 2 blocks/CU (66 KB LDS), 4 waves each
    int nit    = (ntiles + grid - 1) / grid;

    lstmdqn_coop<<<grid, 256, 0, stream>>>(x, h0, c0, Wih, Whh, bih, bhh,
                                           w1, b1, w2, b2, w3, b3, w4, b4, wh, bh,
                                           (float*)d_out, Bsz, ntiles, nit);
}

// Round 5
// 92.663 us; speedup vs baseline: 1.9675x; 1.9675x over previous
//
#include <hip/hip_runtime.h>

typedef _Float16 f16;
typedef _Float16 f16x4 __attribute__((ext_vector_type(4)));
typedef _Float16 f16x8 __attribute__((ext_vector_type(8)));
typedef float    f32x4 __attribute__((ext_vector_type(4)));

__device__ __forceinline__ float sigmf(float x) {
    return __builtin_amdgcn_rcpf(1.0f + __expf(-x));
}
__device__ __forceinline__ float tanhf_fast(float x) {
    return 2.0f * sigmf(2.0f * x) - 1.0f;   // saturates correctly for large |x|
}
#define MFMA(A,B,C) __builtin_amdgcn_mfma_f32_16x16x32_f16((A),(B),(C),0,0,0)

constexpr int STR = 72;   // ABUF row stride (f16): 144B rows -> 16B-aligned frags, <=2-way banks
                          // cols: 0..63 h/z activations, 64..68 x, 69 = 1.0 (bias), 70..71 = 0

__global__ __launch_bounds__(512, 2)
void lstmdqn_v5(const float* __restrict__ xg,  const float* __restrict__ h0g,
                const float* __restrict__ c0g,
                const float* __restrict__ Wih, const float* __restrict__ Whh,
                const float* __restrict__ bih, const float* __restrict__ bhh,
                const float* __restrict__ w1p, const float* __restrict__ b1p,
                const float* __restrict__ w2p, const float* __restrict__ b2p,
                const float* __restrict__ w3p, const float* __restrict__ b3p,
                const float* __restrict__ w4p, const float* __restrict__ b4p,
                const float* __restrict__ whp, const float* __restrict__ bhp,
                float* __restrict__ out, int Bsz, int nt32) {
    __shared__ f16 sAB[256 * STR];    // 36.9 KB activations (8 waves x 32 rows)
    __shared__ f16 sWG[9 * 256 * 8];  // gates W [k>>3][n][k&7]; k: 0..63 Whh | 64..68 Wih | 69 bias | 70,71 zero
    __shared__ f16 sW1[8 * 256 * 8];  // W1 [k>>3][256][k&7], K=64
    __shared__ f16 sW2[32 * 64 * 8];  // W2 [k>>3][64][k&7],  K=256
    __shared__ f16 sW3[8 * 32 * 8];   // W3 K=64, N=32
    __shared__ f16 sW4[4 * 16 * 8];   // W4 K=32, N=16
    __shared__ f16 sWh[4 * 16 * 8];   // Wh K=16 (pad 32 w/ zeros), N=3 (pad 16)
    __shared__ f16 sZL[2560];         // zero slab (covers ct*128 + l*8 range)

    const int tid  = threadIdx.x;
    const int w    = tid >> 6, l = tid & 63;
    const int lrow = l & 15, hi = l >> 4;
    const int wrow = w * 32;

    // ---------------- weight staging (once per block) ----------------
    for (int idx = tid; idx < 9 * 256 * 8; idx += 512) {
        int s = idx >> 11, n = (idx >> 3) & 255, j = idx & 7;
        float v;
        if (s < 8) v = Whh[n * 64 + s * 8 + j];
        else       v = (j < 5) ? Wih[n * 5 + j] : (j == 5 ? bih[n] + bhh[n] : 0.0f);
        sWG[idx] = (f16)v;
    }
    for (int idx = tid; idx < 8 * 256 * 8; idx += 512) {
        int s = idx >> 11, n = (idx >> 3) & 255, j = idx & 7;
        sW1[idx] = (f16)w1p[n * 64 + s * 8 + j];
    }
    for (int idx = tid; idx < 32 * 64 * 8; idx += 512) {
        int s = idx >> 9, n = (idx >> 3) & 63, j = idx & 7;
        sW2[idx] = (f16)w2p[n * 256 + s * 8 + j];
    }
    for (int idx = tid; idx < 8 * 32 * 8; idx += 512) {
        int s = idx >> 8, n = (idx >> 3) & 31, j = idx & 7;
        sW3[idx] = (f16)w3p[n * 64 + s * 8 + j];
    }
    for (int idx = tid; idx < 4 * 16 * 8; idx += 512) {
        int s = idx >> 7, n = (idx >> 3) & 15, j = idx & 7;
        sW4[idx] = (f16)w4p[n * 32 + s * 8 + j];
        int k = s * 8 + j;
        sWh[idx] = (f16)((k < 16 && n < 3) ? whp[n * 16 + k] : 0.0f);
    }
    for (int idx = tid; idx < 2560; idx += 512) sZL[idx] = (f16)0.0f;
    // permanent ABUF columns: 69 = 1.0 (bias feature), 70..71 = 0
    for (int idx = tid; idx < 256 * 3; idx += 512) {
        int r = idx / 3, c = 69 + (idx - 3 * r);
        sAB[r * STR + c] = (f16)(c == 69 ? 1.0f : 0.0f);
    }
    // bias registers (per-lane constants)
    float bz1[16], bz2[4], bz3[2], bz4, bzh;
    #pragma unroll
    for (int ct = 0; ct < 16; ++ct) bz1[ct] = b1p[ct * 16 + lrow];
    #pragma unroll
    for (int ct = 0; ct < 4; ++ct)  bz2[ct] = b2p[ct * 16 + lrow];
    bz3[0] = b3p[lrow]; bz3[1] = b3p[16 + lrow];
    bz4 = b4p[lrow];
    bzh = (lrow < 3) ? bhp[lrow] : 0.0f;
    __syncthreads();
    // ---- from here: each wave touches only its own 32 ABUF rows -> no barriers ----

    // tile-invariant per-lane LDS pointers (everything else folds into immediates)
    const f16* pA[2]  = { &sAB[(wrow +  0 + lrow) * STR + hi * 8],
                          &sAB[(wrow + 16 + lrow) * STR + hi * 8] };
    const f16* pA2[2] = { (hi == 0) ? &sAB[(wrow +  0 + lrow) * STR + 64] : &sZL[l * 8],
                          (hi == 0) ? &sAB[(wrow + 16 + lrow) * STR + 64] : &sZL[l * 8] };
    const f16* pWG  = &sWG[(hi * 256 + lrow) * 8];
    const f16* pWG2 = (hi == 0) ? &sWG[8 * 2048 + lrow * 8] : &sZL[l * 8];
    const f16* pW1  = &sW1[(hi * 256 + lrow) * 8];
    const f16* pW2  = &sW2[(hi * 64 + lrow) * 8];
    const f16* pW3  = &sW3[(hi * 32 + lrow) * 8];
    const f16* pW4  = &sW4[(hi * 16 + lrow) * 8];
    const f16* pWh  = &sWh[(hi * 16 + lrow) * 8];
    int rowW[2][4];
    #pragma unroll
    for (int s = 0; s < 2; ++s)
        #pragma unroll
        for (int q = 0; q < 4; ++q)
            rowW[s][q] = (wrow + 16 * s + 4 * hi + q) * STR + lrow;

    #pragma unroll 1
    for (int tile = blockIdx.x * 8 + w; tile < nt32; tile += (gridDim.x << 3)) {
        const int rbase = tile * 32;

        // ---- stage h0 (32 rows x 64) via float4 loads, b64 LDS writes ----
        {
            const float* hp = h0g + (size_t)rbase * 64;
            #pragma unroll
            for (int e = 0; e < 8; ++e) {
                float4 v = *(const float4*)(hp + e * 256 + l * 4);
                int r = wrow + 4 * e + (l >> 4);
                int col = (4 * l) & 63;
                f16x4 hv = { (f16)v.x, (f16)v.y, (f16)v.z, (f16)v.w };
                *(f16x4*)&sAB[r * STR + col] = hv;
            }
        }
        // ---- c0 -> registers in D layout: creg[s][cg][q] = c[16s+4hi+q][16cg+lrow] ----
        float creg[2][4][4];
        #pragma unroll
        for (int s = 0; s < 2; ++s)
            #pragma unroll
            for (int cg = 0; cg < 4; ++cg)
                #pragma unroll
                for (int q = 0; q < 4; ++q)
                    creg[s][cg][q] = c0g[(size_t)(rbase + 16 * s + 4 * hi + q) * 64 + cg * 16 + lrow];

        // ---- 2 LSTM steps ----
        #pragma unroll
        for (int t = 0; t < 2; ++t) {
            // stage x_t (32 rows x 5) into cols 64..68
            if (l < 40) {
                const float* xp = xg + (size_t)t * Bsz * 5 + (size_t)rbase * 5;
                float4 v = *(const float4*)(xp + 4 * l);
                float vv[4] = { v.x, v.y, v.z, v.w };
                #pragma unroll
                for (int e = 0; e < 4; ++e) {
                    int idx = 4 * l + e, r = idx / 5, ft = idx - 5 * r;
                    sAB[(wrow + r) * STR + 64 + ft] = (f16)vv[e];
                }
            }
            // A fragments: K=96 (kt0,kt1 = h; ktile2 = x|1|0, zero-slab for hi>0)
            f16x8 af0[2], af1[2], af2[2];
            #pragma unroll
            for (int s = 0; s < 2; ++s) {
                af0[s] = *(const f16x8*)&pA[s][0];
                af1[s] = *(const f16x8*)&pA[s][32];
                af2[s] = *(const f16x8*)pA2[s];
            }
            f32x4 acc[2][16];
            #pragma unroll
            for (int ct = 0; ct < 16; ++ct) {
                f16x8 b0 = *(const f16x8*)&pWG[ct * 128];
                f16x8 b1 = *(const f16x8*)&pWG[8192 + ct * 128];
                f16x8 b2 = *(const f16x8*)&pWG2[ct * 128];
                #pragma unroll
                for (int s = 0; s < 2; ++s) {
                    f32x4 a = { 0.f, 0.f, 0.f, 0.f };   // bias folded into k=69 feature
                    a = MFMA(af0[s], b0, a);
                    a = MFMA(af1[s], b1, a);
                    a = MFMA(af2[s], b2, a);
                    acc[s][ct] = a;
                }
            }
            // elementwise cell (i,f,g,o ct-groups 0-3,4-7,8-11,12-15); write h (t=1: relu)
            #pragma unroll
            for (int s = 0; s < 2; ++s)
                #pragma unroll
                for (int cg = 0; cg < 4; ++cg)
                    #pragma unroll
                    for (int q = 0; q < 4; ++q) {
                        float iv = sigmf(acc[s][cg][q]);
                        float fv = sigmf(acc[s][4 + cg][q]);
                        float gv = tanhf_fast(acc[s][8 + cg][q]);
                        float ov = sigmf(acc[s][12 + cg][q]);
                        float c  = fv * creg[s][cg][q] + iv * gv;
                        creg[s][cg][q] = c;
                        float h = ov * tanhf_fast(c);
                        if (t == 1) h = fmaxf(h, 0.0f);
                        sAB[rowW[s][q] + cg * 16] = (f16)h;
                    }
        }

        // ---- z1 = relu(z0 @ W1^T + b1): K=64, N=256 (acc in regs) ----
        f16x8 za[2][2];
        #pragma unroll
        for (int s = 0; s < 2; ++s) {
            za[s][0] = *(const f16x8*)&pA[s][0];
            za[s][1] = *(const f16x8*)&pA[s][32];
        }
        f32x4 acc1[2][16];
        #pragma unroll
        for (int ct = 0; ct < 16; ++ct) {
            f16x8 b0 = *(const f16x8*)&pW1[ct * 128];
            f16x8 b1 = *(const f16x8*)&pW1[8192 + ct * 128];
            #pragma unroll
            for (int s = 0; s < 2; ++s) {
                f32x4 a = { 0.f, 0.f, 0.f, 0.f };
                a = MFMA(za[s][0], b0, a);
                a = MFMA(za[s][1], b1, a);
                acc1[s][ct] = a;
            }
        }
        // ---- z2 = relu(z1 @ W2^T + b2): K=256 in 4 chunks of 64 through cols 0..63 ----
        f32x4 acc2[2][4];
        #pragma unroll
        for (int s = 0; s < 2; ++s)
            #pragma unroll
            for (int ct = 0; ct < 4; ++ct)
                acc2[s][ct] = (f32x4){ 0.f, 0.f, 0.f, 0.f };
        #pragma unroll
        for (int cc = 0; cc < 4; ++cc) {
            #pragma unroll
            for (int s = 0; s < 2; ++s)
                #pragma unroll
                for (int ctl = 0; ctl < 4; ++ctl)
                    #pragma unroll
                    for (int q = 0; q < 4; ++q) {
                        float v = fmaxf(acc1[s][cc * 4 + ctl][q] + bz1[cc * 4 + ctl], 0.0f);
                        sAB[rowW[s][q] + ctl * 16] = (f16)v;
                    }
            f16x8 ca[2][2];
            #pragma unroll
            for (int s = 0; s < 2; ++s) {
                ca[s][0] = *(const f16x8*)&pA[s][0];
                ca[s][1] = *(const f16x8*)&pA[s][32];
            }
            #pragma unroll
            for (int ct2 = 0; ct2 < 4; ++ct2) {
                f16x8 bb0 = *(const f16x8*)&pW2[cc * 4096 + ct2 * 128];
                f16x8 bb1 = *(const f16x8*)&pW2[cc * 4096 + 2048 + ct2 * 128];
                #pragma unroll
                for (int s = 0; s < 2; ++s) {
                    acc2[s][ct2] = MFMA(ca[s][0], bb0, acc2[s][ct2]);
                    acc2[s][ct2] = MFMA(ca[s][1], bb1, acc2[s][ct2]);
                }
            }
        }
        // write z2 (64 feats) to cols 0..63
        #pragma unroll
        for (int s = 0; s < 2; ++s)
            #pragma unroll
            for (int ct2 = 0; ct2 < 4; ++ct2)
                #pragma unroll
                for (int q = 0; q < 4; ++q) {
                    float v = fmaxf(acc2[s][ct2][q] + bz2[ct2], 0.0f);
                    sAB[rowW[s][q] + ct2 * 16] = (f16)v;
                }
        // ---- z3 = relu(z2 @ W3^T + b3): K=64, N=32 -> cols 0..31 ----
        {
            f16x8 a3[2][2];
            #pragma unroll
            for (int s = 0; s < 2; ++s) {
                a3[s][0] = *(const f16x8*)&pA[s][0];
                a3[s][1] = *(const f16x8*)&pA[s][32];
            }
            f32x4 acc3[2][2];
            #pragma unroll
            for (int ctt = 0; ctt < 2; ++ctt) {
                f16x8 c0f = *(const f16x8*)&pW3[ctt * 128];
                f16x8 c1f = *(const f16x8*)&pW3[1024 + ctt * 128];
                #pragma unroll
                for (int s = 0; s < 2; ++s) {
                    f32x4 a = { 0.f, 0.f, 0.f, 0.f };
                    a = MFMA(a3[s][0], c0f, a);
                    a = MFMA(a3[s][1], c1f, a);
                    acc3[s][ctt] = a;
                }
            }
            #pragma unroll
            for (int s = 0; s < 2; ++s)
                #pragma unroll
                for (int ctt = 0; ctt < 2; ++ctt)
                    #pragma unroll
                    for (int q = 0; q < 4; ++q) {
                        float v = fmaxf(acc3[s][ctt][q] + bz3[ctt], 0.0f);
                        sAB[rowW[s][q] + ctt * 16] = (f16)v;
                    }
        }
        // ---- z4 = relu(z3 @ W4^T + b4): K=32 (cols 0..31) -> cols 32..47 ----
        {
            f16x8 wb4 = *(const f16x8*)pW4;
            f32x4 acc4[2];
            #pragma unroll
            for (int s = 0; s < 2; ++s) {
                f16x8 a4 = *(const f16x8*)&pA[s][0];
                f32x4 a = { 0.f, 0.f, 0.f, 0.f };
                acc4[s] = MFMA(a4, wb4, a);
            }
            #pragma unroll
            for (int s = 0; s < 2; ++s)
                #pragma unroll
                for (int q = 0; q < 4; ++q) {
                    float v = fmaxf(acc4[s][q] + bz4, 0.0f);
                    sAB[rowW[s][q] + 32] = (f16)v;
                }
        }
        // ---- head: K=32 over cols 32..63 (cols 48..63 stale x zero weights) ----
        {
            f16x8 wbh = *(const f16x8*)pWh;
            f32x4 acch[2];
            #pragma unroll
            for (int s = 0; s < 2; ++s) {
                f16x8 ah = *(const f16x8*)&pA[s][32];
                f32x4 a = { 0.f, 0.f, 0.f, 0.f };
                acch[s] = MFMA(ah, wbh, a);
            }
            if (lrow < 3) {
                #pragma unroll
                for (int s = 0; s < 2; ++s)
                    #pragma unroll
                    for (int q = 0; q < 4; ++q)
                        out[(size_t)(rbase + 16 * s + 4 * hi + q) * 3 + lrow] = acch[s][q] + bzh;
            }
        }
    }
}

extern "C" void kernel_launch(void* const* d_in, const int* in_sizes, int n_in,
                              void* d_out, int out_size, void* d_ws, size_t ws_size,
                              hipStream_t stream) {
    const float* x   = (const float*)d_in[0];
    const float* h0  = (const float*)d_in[1];
    const float* c0  = (const float*)d_in[2];
    const float* Wih = (const float*)d_in[3];
    const float* Whh = (const float*)d_in[4];
    const float* bih = (const float*)d_in[5];
    const float* bhh = (const float*)d_in[6];
    const float* w1  = (const float*)d_in[7];
    const float* b1  = (const float*)d_in[8];
    const float* w2  = (const float*)d_in[9];
    const float* b2  = (const float*)d_in[10];
    const float* w3  = (const float*)d_in[11];
    const float* b3  = (const float*)d_in[12];
    const float* w4  = (const float*)d_in[13];
    const float* b4  = (const float*)d_in[14];
    const float* wh  = (const float*)d_in[15];
    const float* bh  = (const float*)d_in[16];

    int Bsz  = in_sizes[1] / 64;   // h0 is [B, 64]
    int nt32 = Bsz / 32;           // 32-row tiles
    int grid = 256;                // 1 block/CU persistent; 8 waves x 32 rows; 4 iters

    lstmdqn_v5<<<grid, 512, 0, stream>>>(x, h0, c0, Wih, Whh, bih, bhh,
                                         w1, b1, w2, b2, w3, b3, w4, b4, wh, bh,
                                         (float*)d_out, Bsz, nt32);
}